// Round 4
// baseline (104.309 us; speedup 1.0000x reference)
//
#include <hip/hip_runtime.h>
#include <hip/hip_bf16.h>

#define NCAM   16
#define IN     256
#define OUT    128
#define BATCH  8192
#define CAP    8192            // per-camera list capacity (worst case)
#define MT     32              // samples per GEMM tile
#define NTILE  (CAP / MT)      // 256 tiles/cam; ~240 early-exit at E[cnt]=512
#define XROWW  (IN + 8)        // padded bf16 row stride: 528 B -> 2-way banks (free)

typedef short bfx8 __attribute__((ext_vector_type(8)));   // MFMA A/B frag (4 VGPRs)
typedef short bfx4 __attribute__((ext_vector_type(4)));
typedef float fx4  __attribute__((ext_vector_type(4)));   // MFMA C/D frag

__device__ inline short f2bf(float f) {
    __hip_bfloat16 h = __float2bfloat16(f);   // RNE
    return *reinterpret_cast<short*>(&h);
}

__device__ inline float sigmoidf(float v) {
    return 1.0f / (1.0f + __expf(-v));
}

// ---- K0: zero the per-camera counters (ws is re-poisoned 0xAA every call) ----
__global__ void zero_cnt_kernel(int* __restrict__ cnt) {
    if (threadIdx.x < NCAM) cnt[threadIdx.x] = 0;
}

// ---- K1: dense per-camera index lists via per-lane atomicAdd (order-free) ----
__global__ void compact_kernel(const int* __restrict__ cam,
                               int* __restrict__ cnt,
                               int* __restrict__ list) {
    int g = blockIdx.x * 256 + threadIdx.x;
    int c = cam[g];
    int slot = atomicAdd(&cnt[c], 1);   // HW serializes same-address lanes; 1 instr
    list[c * CAP + slot] = g;
}

// ---- K2: grouped GEMM. Block = (tile, camera). W[c] staged bf16 in LDS once
// (coalesced: one 1KB row per wave-instruction); A-frags gathered from global
// in layout-exact 16B chunks; 16x16x32 MFMA; bias+sigmoid epilogue. ----
__global__ __launch_bounds__(256, 2) void gemm_kernel(
    const float* __restrict__ x,     // [BATCH, IN]
    const float* __restrict__ W,     // [NCAM, OUT, IN]
    const float* __restrict__ bias,  // [NCAM, OUT]
    const int*   __restrict__ cnt,   // [NCAM]
    const int*   __restrict__ list,  // [NCAM, CAP]
    float*       __restrict__ out)   // [BATCH, OUT]
{
    __shared__ short __align__(16) s_w[OUT * XROWW];   // 67.6 KB -> 2 blocks/CU

    const int t = blockIdx.x;
    const int c = blockIdx.y;
    const int m_all = cnt[c];
    const int base  = t * MT;
    if (base >= m_all) return;                 // drained tiles exit immediately
    const int m = min(MT, m_all - base);

    const int tid  = threadIdx.x;
    const int lane = tid & 63;
    const int w    = tid >> 6;                 // wave 0..3: outputs [w*32, w*32+32)
    const int oq   = lane & 15;
    const int quad = lane >> 4;

    // stage W[c] rows [w*32, w*32+32): one full row per wave-instruction (coalesced)
    {
        const float* wp = W + (size_t)c * OUT * IN;
        #pragma unroll
        for (int i = 0; i < 32; ++i) {
            const int row = w * 32 + i;
            fx4 v = *(const fx4*)(wp + (size_t)row * IN + lane * 4);
            bfx4 sv;
            sv[0] = f2bf(v[0]); sv[1] = f2bf(v[1]); sv[2] = f2bf(v[2]); sv[3] = f2bf(v[3]);
            *(bfx4*)(s_w + row * XROWW + lane * 4) = sv;   // 8B/lane, 2-way banks
        }
    }
    const float b0 = bias[c * OUT + w * 32 + oq];
    const float b1 = bias[c * OUT + w * 32 + 16 + oq];
    __syncthreads();                            // the only barrier in the kernel

    const int* lst = list + c * CAP + base;

    for (int cb = 0; cb < m; cb += 16) {
        // A-frags straight from global: lane(oq,quad) reads x[g(oq)][quad*8 + kk*32 ..+8)
        const int li = cb + oq;
        const int g  = lst[min(li, m - 1)];     // clamp: padded rows never stored
        const float* xr = x + (size_t)g * IN + quad * 8;
        bfx8 afrag[8];
        #pragma unroll
        for (int kk = 0; kk < 8; ++kk) {
            fx4 a0 = *(const fx4*)(xr + kk * 32);
            fx4 a1 = *(const fx4*)(xr + kk * 32 + 4);
            bfx8 s;
            s[0] = f2bf(a0[0]); s[1] = f2bf(a0[1]); s[2] = f2bf(a0[2]); s[3] = f2bf(a0[3]);
            s[4] = f2bf(a1[0]); s[5] = f2bf(a1[1]); s[6] = f2bf(a1[2]); s[7] = f2bf(a1[3]);
            afrag[kk] = s;
        }

        fx4 acc0 = {0.f, 0.f, 0.f, 0.f};
        fx4 acc1 = {0.f, 0.f, 0.f, 0.f};
        #pragma unroll
        for (int kk = 0; kk < 8; ++kk) {
            bfx8 bv0 = *(const bfx8*)(s_w + (w * 32 + oq) * XROWW + kk * 32 + quad * 8);
            bfx8 bv1 = *(const bfx8*)(s_w + (w * 32 + 16 + oq) * XROWW + kk * 32 + quad * 8);
            acc0 = __builtin_amdgcn_mfma_f32_16x16x32_bf16(afrag[kk], bv0, acc0, 0, 0, 0);
            acc1 = __builtin_amdgcn_mfma_f32_16x16x32_bf16(afrag[kk], bv1, acc1, 0, 0, 0);
        }

        // epilogue: C/D col=lane&15 (output), row=quad*4+r (sample)
        #pragma unroll
        for (int r = 0; r < 4; ++r) {
            const int srow = quad * 4 + r;
            if (cb + srow < m) {
                const int gs = lst[cb + srow];
                float* op = out + (size_t)gs * OUT + w * 32 + oq;
                op[0]  = sigmoidf(acc0[r] + b0);
                op[16] = sigmoidf(acc1[r] + b1);
            }
        }
    }
}

extern "C" void kernel_launch(void* const* d_in, const int* in_sizes, int n_in,
                              void* d_out, int out_size, void* d_ws, size_t ws_size,
                              hipStream_t stream) {
    const float* x    = (const float*)d_in[0];
    const int*   cam  = (const int*)d_in[1];
    const float* W    = (const float*)d_in[2];
    const float* bias = (const float*)d_in[3];
    float* out = (float*)d_out;

    int* cnt  = (int*)d_ws;
    int* list = (int*)((char*)d_ws + 256);     // 16*CAP ints = 512 KB

    zero_cnt_kernel<<<1, 64, 0, stream>>>(cnt);
    compact_kernel<<<BATCH / 256, 256, 0, stream>>>(cam, cnt, list);
    dim3 grid(NTILE, NCAM);
    gemm_kernel<<<grid, 256, 0, stream>>>(x, W, bias, cnt, list, out);
}

// Round 5
// 73.773 us; speedup vs baseline: 1.4139x; 1.4139x over previous
//
#include <hip/hip_runtime.h>
#include <hip/hip_bf16.h>

#define NCAM   16
#define IN     256
#define OUT    128
#define BATCH  8192
#define NSLICE 32
#define SLICE  (BATCH / NSLICE)   // 256 samples per block's scan range
#define OHALF  64                 // outputs per block (z-split by 2)
#define XROW   (IN + 8)           // padded bf16 row stride (528 B): 2-way banks = free

typedef short bfx8 __attribute__((ext_vector_type(8)));   // MFMA A/B frag (4 VGPRs)
typedef short bfx4 __attribute__((ext_vector_type(4)));
typedef float fx4  __attribute__((ext_vector_type(4)));   // MFMA C/D frag

__device__ inline short f2bf(float f) {
    __hip_bfloat16 h = __float2bfloat16(f);   // RNE
    return *reinterpret_cast<short*>(&h);
}

__device__ inline float sigmoidf(float v) {
    return 1.0f / (1.0f + __expf(-v));
}

// Block = (slice, camera, out-half): 1024 blocks, 3/CU (LDS-limited).
// One-pass 4-wave ballot compaction; W staged COALESCED via LDS (full-row
// loads, bf16), x staged coalesced via LDS; 16x16x32 MFMA; fused sigmoid.
__global__ __launch_bounds__(256, 3) void fc_expert_kernel(
    const float* __restrict__ x,     // [BATCH, IN] fp32
    const int*   __restrict__ cam,   // [BATCH]
    const float* __restrict__ W,     // [NCAM, OUT, IN] fp32
    const float* __restrict__ bias,  // [NCAM, OUT] fp32
    float*       __restrict__ out)   // [BATCH, OUT] fp32
{
    __shared__ int   s_list[SLICE];
    __shared__ int   s_cnt[4];
    __shared__ short __align__(16) s_w[OHALF * XROW];  // 33.8 KB bf16 W strip
    __shared__ short __align__(16) s_x[16 * XROW];     //  8.4 KB x chunk

    const int slice = blockIdx.x;
    const int c     = blockIdx.y;
    const int obase = blockIdx.z * OHALF;
    const int tid   = threadIdx.x;
    const int lane  = tid & 63;
    const int w     = tid >> 6;          // wave 0..3; owns outputs [obase+w*16, +16)
    const int base  = slice * SLICE;

    const int oq   = lane & 15;
    const int quad = lane >> 4;

    // ---- issue scan load, then W row loads (independent; VMEM pipelines) ----
    const int g0  = base + w * 64 + lane;
    const int myc = cam[g0];

    // wave w stages W rows [obase + w*16, +16): one full coalesced row per instr
    const float* wp = W + (size_t)(c * OUT + obase + w * 16) * IN;
    fx4 wv[16];
    #pragma unroll
    for (int i = 0; i < 16; ++i)
        wv[i] = *(const fx4*)(wp + (size_t)i * IN + lane * 4);

    const float bo = bias[c * OUT + obase + w * 16 + oq];

    // ---- one-pass compaction: each wave ballots its 64 entries ----
    const bool f = (myc == c);
    const unsigned long long mask = __ballot(f);
    if (lane == 0) s_cnt[w] = __popcll(mask);
    __syncthreads();
    int off = 0;
    #pragma unroll
    for (int ww = 0; ww < 4; ++ww) off += (ww < w) ? s_cnt[ww] : 0;
    const int m = s_cnt[0] + s_cnt[1] + s_cnt[2] + s_cnt[3];
    const int pre = __popcll(mask & ((1ull << lane) - 1ull));
    if (f) s_list[off + pre] = g0;

    // ---- convert staged W rows to bf16 in LDS (8 B/lane writes, 2-way banks) ----
    #pragma unroll
    for (int i = 0; i < 16; ++i) {
        fx4 v = wv[i];
        bfx4 sv;
        sv[0] = f2bf(v[0]); sv[1] = f2bf(v[1]); sv[2] = f2bf(v[2]); sv[3] = f2bf(v[3]);
        *(bfx4*)(s_w + (w * 16 + i) * XROW + lane * 4) = sv;
    }
    __syncthreads();   // covers s_list + s_w

    for (int cb = 0; cb < m; cb += 16) {
        // ---- stage up to 16 gathered x rows into LDS (full-row coalesced) ----
        #pragma unroll
        for (int rr = 0; rr < 4; ++rr) {
            int row = rr * 4 + w;
            int li  = cb + row;
            bfx4 sv;
            if (li < m) {
                int g = s_list[li];
                fx4 v = *(const fx4*)(x + (size_t)g * IN + lane * 4);
                sv[0] = f2bf(v[0]); sv[1] = f2bf(v[1]); sv[2] = f2bf(v[2]); sv[3] = f2bf(v[3]);
            } else {
                sv[0] = 0; sv[1] = 0; sv[2] = 0; sv[3] = 0;
            }
            *(bfx4*)(s_x + row * XROW + lane * 4) = sv;
        }
        __syncthreads();

        // ---- MFMA: 16 samples x 16 outputs, K=256; A and B both from LDS ----
        fx4 acc = {0.f, 0.f, 0.f, 0.f};
        #pragma unroll
        for (int kk = 0; kk < 8; ++kk) {
            bfx8 a = *(const bfx8*)(s_x + oq * XROW + kk * 32 + quad * 8);
            bfx8 b = *(const bfx8*)(s_w + (w * 16 + oq) * XROW + kk * 32 + quad * 8);
            acc = __builtin_amdgcn_mfma_f32_16x16x32_bf16(a, b, acc, 0, 0, 0);
        }

        // ---- epilogue: bias + sigmoid + scatter (C/D: col=lane&15, row=quad*4+r) ----
        #pragma unroll
        for (int r = 0; r < 4; ++r) {
            int srow = quad * 4 + r;
            if (cb + srow < m) {
                int g = s_list[cb + srow];
                out[(size_t)g * OUT + obase + w * 16 + oq] = sigmoidf(acc[r] + bo);
            }
        }
        __syncthreads();   // s_x reads done before next chunk's staging
    }
}

extern "C" void kernel_launch(void* const* d_in, const int* in_sizes, int n_in,
                              void* d_out, int out_size, void* d_ws, size_t ws_size,
                              hipStream_t stream) {
    const float* x    = (const float*)d_in[0];
    const int*   cam  = (const int*)d_in[1];
    const float* W    = (const float*)d_in[2];
    const float* bias = (const float*)d_in[3];
    float* out = (float*)d_out;

    dim3 grid(NSLICE, NCAM, 2);
    fc_expert_kernel<<<grid, 256, 0, stream>>>(x, cam, W, bias, out);
}